// Round 11
// baseline (299.649 us; speedup 1.0000x reference)
//
#include <hip/hip_runtime.h>
#include <hip/hip_bf16.h>
#include <stdint.h>

// EMASpitDelta: B=128, L=4096, H=64, V=64, HALF=32, ALPHA=0.95
// V=64 -> token pipeline collapses to a 64-entry table (build_tables).
// r = M_final q = sum_t b_t (k_t^T z_t) h_t with backward vector scan
// z <- z - b_t (k_t^T z) k_t (A_t symmetric). Chunk-parallel (CCH=64):
//  k2: per-chunk transition matrices P_c (LDS-broadcast k, row-per-lane)
//  k3 (tail, FUSED): per (b,mat) single-wave kernel: fold z backward through
//     the 64 P_c (prefetched), then 64 parallel per-chunk backward vector
//     scans (lane = chunk), then in-wave reduction -> rv. Wave-synchronous,
//     no __syncthreads in the serial loops.
//  k4: readout GEMVs.
// Inputs fp32 or bf16 (runtime-detected from gamma bit pattern).

#define BETA 0.05f
#define NB 128
#define NL 4096
#define NSTEPS 4095
#define CCH 64          // chunks per (b, mat)
#define CLEN 64         // chunk length (CCH*CLEN = 4096)

__device__ __forceinline__ float ldf(const void* p, int i, int isbf) {
    return isbf ? __bfloat162float(((const __hip_bfloat16*)p)[i])
                : ((const float*)p)[i];
}

// ---------------- Kernel 1: per-token-value tables ----------------
// grid 64 (token v), block 64 (feature j). tbl (f32):
// [0..2047]=hs, [2048..4095]=ks(norm), [4096..6143]=he, [6144..8191]=ke
__global__ __launch_bounds__(64, 2) void build_tables(
    const void* embed, const void* W1, const void* b1, const void* W2,
    const void* b2, const void* ln_g, const void* ln_b,
    const void* Ws, const void* bs, const void* We, const void* be,
    float* __restrict__ tbl)
{
    int v = blockIdx.x;
    int j = threadIdx.x;
    int isbf = (*(const uint32_t*)ln_g == 0x3F803F80u) ? 1 : 0;
    __shared__ float h0s[64];
    __shared__ float act[128];
    __shared__ float hrow[64];

    float h0 = ldf(embed, v * 64 + j, isbf);
    h0s[j] = h0;
    __syncthreads();

    float za = ldf(b1, j, isbf);
    float zb = ldf(b1, j + 64, isbf);
    for (int k = 0; k < 64; ++k) {
        float hk = h0s[k];
        za = fmaf(hk, ldf(W1, k * 128 + j, isbf), za);
        zb = fmaf(hk, ldf(W1, k * 128 + j + 64, isbf), zb);
    }
    act[j] = fmaxf(za, 0.0f);
    act[j + 64] = fmaxf(zb, 0.0f);
    __syncthreads();

    float ff = ldf(b2, j, isbf);
    for (int k = 0; k < 128; ++k)
        ff = fmaf(act[k], ldf(W2, k * 64 + j, isbf), ff);
    float x = h0 + ff;

    float s = x;
    for (int off = 32; off >= 1; off >>= 1) s += __shfl_xor(s, off, 64);
    float mu = s * (1.0f / 64.0f);
    float d = x - mu;
    float s2 = d * d;
    for (int off = 32; off >= 1; off >>= 1) s2 += __shfl_xor(s2, off, 64);
    float var = s2 * (1.0f / 64.0f);
    float h = d / sqrtf(var + 1e-5f) * ldf(ln_g, j, isbf) + ldf(ln_b, j, isbf);
    hrow[j] = h;
    __syncthreads();

    if (j < 32) {
        float sv = ldf(bs, j, isbf);
        for (int k = 0; k < 64; ++k)
            sv = fmaf(hrow[k], ldf(Ws, k * 32 + j, isbf), sv);
        float n2 = sv * sv;
        for (int off = 16; off >= 1; off >>= 1) n2 += __shfl_xor(n2, off, 64);
        float nrm = fmaxf(sqrtf(n2), 1e-12f);
        tbl[v * 32 + j] = sv;
        tbl[2048 + v * 32 + j] = sv / nrm;
    } else {
        int jj = j - 32;
        float ev = ldf(be, jj, isbf);
        for (int k = 0; k < 64; ++k)
            ev = fmaf(hrow[k], ldf(We, k * 32 + jj, isbf), ev);
        float n2 = ev * ev;
        for (int off = 16; off >= 1; off >>= 1) n2 += __shfl_xor(n2, off, 64);
        float nrm = fmaxf(sqrtf(n2), 1e-12f);
        tbl[4096 + v * 32 + jj] = ev;
        tbl[6144 + v * 32 + jj] = ev / nrm;
    }
}

// ---------------- Kernel 2: P-only chunk scan -----------------------------
// grid = NB*16 = 2048 blocks, 256 threads = 4 waves; wave -> (mat, 2 chunks
// via half-wave); lane r = lane&31 owns P[r,:].
#define DOT4(a, b) fmaf((a).x, (b).x, fmaf((a).y, (b).y, fmaf((a).z, (b).z, (a).w * (b).w)))
#define UPD4(p, k) { (p).x = fmaf(cp, (k).x, (p).x); (p).y = fmaf(cp, (k).y, (p).y); \
                     (p).z = fmaf(cp, (k).z, (p).z); (p).w = fmaf(cp, (k).w, (p).w); }

__global__ __launch_bounds__(256, 3) void chunk_scan_p(
    const int* __restrict__ seq, const float* __restrict__ tbl,
    float* __restrict__ Pbuf)
{
    __shared__ float kl[4096];      // [mat][v][j] normalized k tables (16 KB)
    __shared__ int tk[4][CLEN];     // tokens for the block's 4 chunks

    int tid = threadIdx.x;
    int b = blockIdx.x >> 4;
    int quad = blockIdx.x & 15;
    int c0 = quad * 4;

    for (int i = tid; i < 2048; i += 256) {
        kl[i] = tbl[2048 + i];          // ks
        kl[2048 + i] = tbl[6144 + i];   // ke
    }
    for (int s = 0; s < 4; ++s) {
        int t0s = (c0 + s) * CLEN;
        for (int i = tid; i < CLEN; i += 256) {
            int t = t0s + i;
            tk[s][i] = (t < NSTEPS) ? seq[b * NL + t] : 0;
        }
    }
    __syncthreads();

    int w = tid >> 6;
    int lane = tid & 63;
    int mat = w & 1;
    int sloc = (w >> 1) * 2 + (lane >> 5);
    int c = c0 + sloc;
    int r = lane & 31;

    const float* kt = kl + mat * 2048;
    const int* tks = tk[sloc];

    int t0 = c * CLEN;
    int clen = NSTEPS - t0;
    if (clen > CLEN) clen = CLEN;

    float4 p0 = make_float4(r == 0, r == 1, r == 2, r == 3);
    float4 p1 = make_float4(r == 4, r == 5, r == 6, r == 7);
    float4 p2 = make_float4(r == 8, r == 9, r == 10, r == 11);
    float4 p3 = make_float4(r == 12, r == 13, r == 14, r == 15);
    float4 p4 = make_float4(r == 16, r == 17, r == 18, r == 19);
    float4 p5 = make_float4(r == 20, r == 21, r == 22, r == 23);
    float4 p6 = make_float4(r == 24, r == 25, r == 26, r == 27);
    float4 p7 = make_float4(r == 28, r == 29, r == 30, r == 31);

    const float bstep = BETA * (1.0f / 4096.0f);
    float bmul = mat ? bstep : 0.0f;
    float badd = mat ? 0.0f : BETA;

    for (int it = 0; it < CLEN; ++it) {
        int v = tks[it];
        const float4* kp = (const float4*)(kt + v * 32);
        float4 k0 = kp[0], k1 = kp[1], k2 = kp[2], k3 = kp[3];
        float4 k4 = kp[4], k5 = kp[5], k6 = kp[6], k7 = kp[7];
        float bsc = fmaf(bmul, (float)(t0 + it + 1), badd);
        if (it >= clen) bsc = 0.0f;

        float da = DOT4(p0, k0) + DOT4(p1, k1);
        float db = DOT4(p2, k2) + DOT4(p3, k3);
        float dc = DOT4(p4, k4) + DOT4(p5, k5);
        float dd = DOT4(p6, k6) + DOT4(p7, k7);
        float cp = -bsc * ((da + db) + (dc + dd));
        UPD4(p0, k0) UPD4(p1, k1) UPD4(p2, k2) UPD4(p3, k3)
        UPD4(p4, k4) UPD4(p5, k5) UPD4(p6, k6) UPD4(p7, k7)
    }

    float4* pd = (float4*)(Pbuf + (((size_t)b * 2 + mat) * CCH + c) * 1024 + r * 32);
    pd[0] = p0; pd[1] = p1; pd[2] = p2; pd[3] = p3;
    pd[4] = p4; pd[5] = p5; pd[6] = p6; pd[7] = p7;
}

// ---------------- Kernel 3: fused tail (fold z + suffix scans + reduce) ---
// grid = NB*2 blocks (b,mat), 64 threads = ONE wave (wave-synchronous: no
// __syncthreads in the serial loops). Phase A: fold z backward through the
// 64 P_c (global, row-per-lane, prefetched), storing z at every chunk
// boundary in LDS. Phase B: lane = chunk, 64-step backward vector scan from
// LDS tables (33-stride padding -> spread banks). Phase C: reduce racc.
__global__ __launch_bounds__(64, 1) void tail(
    const int* __restrict__ seq, const float* __restrict__ tbl,
    const float* __restrict__ Pbuf, float* __restrict__ rvbuf)
{
    __shared__ float klp[64 * 33];
    __shared__ float hlp[64 * 33];
    __shared__ float zin[64 * 33];
    __shared__ float red[64 * 33];
    __shared__ float zl[32];
    __shared__ int tkT[64 * 64];    // [it][c]

    int bm = blockIdx.x;
    int b = bm >> 1, mat = bm & 1;
    int lane = threadIdx.x;

    // stage tables + tokens (single wave, in-order)
    for (int i = lane; i < 2048; i += 64) {
        int v = i >> 5, j = i & 31;
        klp[v * 33 + j] = tbl[2048 + mat * 4096 + i];
        hlp[v * 33 + j] = tbl[mat * 4096 + i];
    }
    for (int i = lane; i < 4096; i += 64) {
        int c = i >> 6, it = i & 63;
        tkT[it * 64 + c] = seq[b * NL + i];   // coalesced read
    }

    // ---- Phase A: fold z backward through chunks (lanes 0-31 active) ----
    int vlast = seq[b * NL + NL - 1];
    int r = lane & 31;
    int act = (lane < 32);
    if (act) zl[r] = klp[vlast * 33 + r];     // q = normalized key row

    const float* Pb = Pbuf + (size_t)bm * CCH * 1024;
    float4 cur[8];
    if (act) {
        const float4* src = (const float4*)(Pb + (size_t)(CCH - 1) * 1024 + r * 32);
#pragma unroll
        for (int i = 0; i < 8; ++i) cur[i] = src[i];
    }

    for (int c = CCH - 1; c >= 0; --c) {
        float zr = 0.0f;
        if (act) zr = zl[r];
        if (act) zin[c * 33 + r] = zr;
        float4 nxt[8];
        if (act && c > 0) {
            const float4* src = (const float4*)(Pb + (size_t)(c - 1) * 1024 + r * 32);
#pragma unroll
            for (int i = 0; i < 8; ++i) nxt[i] = src[i];   // indep of zl
        }
        float y = 0.0f;
        if (act) {
            float a0 = 0.f, a1 = 0.f, a2 = 0.f, a3 = 0.f;
#pragma unroll
            for (int i = 0; i < 8; ++i) {
                const float* zp = zl + 4 * i;              // broadcast reads
                a0 = fmaf(cur[i].x, zp[0], a0);
                a1 = fmaf(cur[i].y, zp[1], a1);
                a2 = fmaf(cur[i].z, zp[2], a2);
                a3 = fmaf(cur[i].w, zp[3], a3);
            }
            y = (a0 + a1) + (a2 + a3);
        }
        // wave-synchronous: all zl reads above retire before this store
        if (act) zl[r] = y;
        if (act && c > 0) {
#pragma unroll
            for (int i = 0; i < 8; ++i) cur[i] = nxt[i];
        }
    }

    // ---- Phase B: per-chunk backward vector scans (lane = chunk) ----
    int c = lane;
    int t0 = c * CLEN;
    float z[32], racc[32];
#pragma unroll
    for (int j = 0; j < 32; ++j) {
        z[j] = zin[c * 33 + j];               // banks (c+j)&31 -> spread
        racc[j] = 0.0f;
    }

    const float bstep = BETA * (1.0f / 4096.0f);
    float bmul = mat ? bstep : 0.0f;
    float badd = mat ? 0.0f : BETA;

    for (int it = CLEN - 1; it >= 0; --it) {
        int t = t0 + it;
        int v = tkT[it * 64 + c];             // 2-way banks, free
        const float* kp = klp + v * 33;
        const float* hp = hlp + v * 33;
        float bsc = fmaf(bmul, (float)(t + 1), badd);
        if (t >= NSTEPS) bsc = 0.0f;          // only t=4095

        float d0 = 0.f, d1 = 0.f, d2 = 0.f, d3 = 0.f;
#pragma unroll
        for (int j = 0; j < 32; j += 4) {
            d0 = fmaf(z[j + 0], kp[j + 0], d0);
            d1 = fmaf(z[j + 1], kp[j + 1], d1);
            d2 = fmaf(z[j + 2], kp[j + 2], d2);
            d3 = fmaf(z[j + 3], kp[j + 3], d3);
        }
        float d = ((d0 + d1) + (d2 + d3)) * bsc;
#pragma unroll
        for (int j = 0; j < 32; ++j) {
            racc[j] = fmaf(d, hp[j], racc[j]);
            z[j] = fmaf(-d, kp[j], z[j]);
        }
    }

    // ---- Phase C: reduce racc over the 64 chunk-lanes ----
#pragma unroll
    for (int j = 0; j < 32; ++j) red[lane * 33 + j] = racc[j];
    if (lane < 32) {
        float s = 0.0f;
        for (int l = 0; l < 64; ++l) s += red[l * 33 + lane];  // conflict-free
        rvbuf[(size_t)bm * 32 + lane] = s;
    }
}

// ---------------- Kernel 4: readout projections ---------------------------
__global__ __launch_bounds__(64, 2) void readout(
    const float* __restrict__ rvbuf,
    const void* Wrp, const void* brp, const void* Wout, const void* bout,
    const void* ln_g, void* __restrict__ outv)
{
    __shared__ float rv[64];
    __shared__ float o1s[64];
    int b = blockIdx.x;
    int tid = threadIdx.x;
    int isbf = (*(const uint32_t*)ln_g == 0x3F803F80u) ? 1 : 0;

    rv[tid] = rvbuf[b * 64 + tid];   // [rs | re]
    __syncthreads();
    float o = ldf(brp, tid, isbf);
    for (int i = 0; i < 64; ++i)
        o = fmaf(rv[i], ldf(Wrp, i * 64 + tid, isbf), o);
    o1s[tid] = o;
    __syncthreads();
    float o2 = ldf(bout, tid, isbf);
    for (int i = 0; i < 64; ++i)
        o2 = fmaf(o1s[i], ldf(Wout, i * 64 + tid, isbf), o2);
    if (isbf)
        ((__hip_bfloat16*)outv)[b * 64 + tid] = __float2bfloat16(o2);
    else
        ((float*)outv)[b * 64 + tid] = o2;
}

extern "C" void kernel_launch(void* const* d_in, const int* in_sizes, int n_in,
                              void* d_out, int out_size, void* d_ws, size_t ws_size,
                              hipStream_t stream) {
    const int* seq = (const int*)d_in[0];
    const void* embed = d_in[1];
    const void* W1 = d_in[2];
    const void* b1 = d_in[3];
    const void* W2 = d_in[4];
    const void* b2 = d_in[5];
    const void* ln_g = d_in[6];
    const void* ln_b = d_in[7];
    const void* Ws = d_in[8];
    const void* bs = d_in[9];
    const void* We = d_in[10];
    const void* be = d_in[11];
    const void* Wrp = d_in[12];
    const void* brp = d_in[13];
    const void* Wout = d_in[14];
    const void* bout = d_in[15];

    // ws (floats): tbl[8192] | Pbuf[256*64*1024] | rvbuf[8192]
    float* tbl = (float*)d_ws;
    float* Pbuf = tbl + 8192;
    size_t PN = (size_t)NB * 2 * CCH * 1024;   // 16.8M floats
    float* rvbuf = Pbuf + PN;

    build_tables<<<64, 64, 0, stream>>>(embed, W1, b1, W2, b2, ln_g, ln_b,
                                        Ws, bs, We, be, tbl);
    chunk_scan_p<<<NB * 16, 256, 0, stream>>>(seq, tbl, Pbuf);
    tail<<<NB * 2, 64, 0, stream>>>(seq, tbl, Pbuf, rvbuf);
    readout<<<NB, 64, 0, stream>>>(rvbuf, Wrp, brp, Wout, bout, ln_g, d_out);
}

// Round 12
// 280.380 us; speedup vs baseline: 1.0687x; 1.0687x over previous
//
#include <hip/hip_runtime.h>
#include <hip/hip_bf16.h>
#include <stdint.h>

// EMASpitDelta: B=128, L=4096, H=64, V=64, HALF=32, ALPHA=0.95
// V=64 -> token pipeline collapses to a 64-entry table.
// r = M_final q = sum_t b_t (k_t^T z_t) h_t with backward vector scan
// z <- z - b_t (k_t^T z) k_t (A_t symmetric). Chunk-parallel (CCH=64):
//  k2: per-chunk transition matrices P_c. R12 layout: HALF-ROW per lane --
//      lane (hf,r) owns P[r][hf*16..+15] (16 regs) + k half (16 regs), so the
//      full live set fits in arch VGPRs (R7-R11: full-row layout pinned
//      VGPR=52 < live 64+ -> compiler re-read k from LDS, ~3x VALU bloat).
//      Dot combined across halves with one __shfl_xor(.,32).
//  k3: fold z backward through the 64 P_c (split kernels measured faster
//      than fused tail: R10 273us vs R11 300us).
//  k4: per-chunk backward vector scans (lane = chunk) + in-block reduce.
//  k5: readout GEMVs. Weights in fp32 arena (k0).

#define BETA 0.05f
#define NB 128
#define NL 4096
#define NSTEPS 4095
#define CCH 64          // chunks per (b, mat)
#define CLEN 64         // chunk length (CCH*CLEN = 4096)

// fp32 arena offsets (floats)
#define A_EMBED 0
#define A_W1    4096
#define A_B1    12288
#define A_W2    12416
#define A_B2    20608
#define A_GAMMA 20672
#define A_BETA  20736
#define A_WSM   20800
#define A_BS    22848
#define A_WEM   22880
#define A_BE    24928
#define A_WRP   24960
#define A_BRP   29056
#define A_WOUT  29120
#define A_BOUT  33216
#define A_TOTAL 33280

struct Ptrs { const void* p[15]; };

// ---------------- Kernel 0: detect dtype + convert to fp32 arena ----------
__global__ __launch_bounds__(256) void convert_inputs(Ptrs ps, float* __restrict__ arena)
{
    const int sizes[15] = {4096, 8192, 128, 8192, 64, 64, 64, 2048, 32, 2048, 32, 4096, 64, 4096, 64};
    const int offs[15] = {A_EMBED, A_W1, A_B1, A_W2, A_B2, A_GAMMA, A_BETA,
                          A_WSM, A_BS, A_WEM, A_BE, A_WRP, A_BRP, A_WOUT, A_BOUT};
    uint32_t g0 = *(const uint32_t*)ps.p[5];
    int isbf = (g0 == 0x3F803F80u) ? 1 : 0;
    int t = blockIdx.x;
    const void* src = ps.p[t];
    float* dst = arena + offs[t];
    int n = sizes[t];
    if (isbf) {
        const __hip_bfloat16* s = (const __hip_bfloat16*)src;
        for (int i = threadIdx.x; i < n; i += 256) dst[i] = __bfloat162float(s[i]);
    } else {
        const float* s = (const float*)src;
        for (int i = threadIdx.x; i < n; i += 256) dst[i] = s[i];
    }
}

// ---------------- Kernel 1: per-token-value tables ----------------
// grid 64 (token v), block 64 (feature j). tbl (f32):
// [0..2047]=hs, [2048..4095]=ks(norm), [4096..6143]=he, [6144..8191]=ke
__global__ __launch_bounds__(64, 2) void build_tables(const float* __restrict__ A,
                                                      float* __restrict__ tbl)
{
    int v = blockIdx.x;
    int j = threadIdx.x;
    __shared__ float h0s[64];
    __shared__ float act[128];
    __shared__ float hrow[64];

    float h0 = A[A_EMBED + v * 64 + j];
    h0s[j] = h0;
    __syncthreads();

    float za = A[A_B1 + j];
    float zb = A[A_B1 + j + 64];
    for (int k = 0; k < 64; ++k) {
        float hk = h0s[k];
        za = fmaf(hk, A[A_W1 + k * 128 + j], za);
        zb = fmaf(hk, A[A_W1 + k * 128 + j + 64], zb);
    }
    act[j] = fmaxf(za, 0.0f);
    act[j + 64] = fmaxf(zb, 0.0f);
    __syncthreads();

    float ff = A[A_B2 + j];
    for (int k = 0; k < 128; ++k)
        ff = fmaf(act[k], A[A_W2 + k * 64 + j], ff);
    float x = h0 + ff;

    float s = x;
    for (int off = 32; off >= 1; off >>= 1) s += __shfl_xor(s, off, 64);
    float mu = s * (1.0f / 64.0f);
    float d = x - mu;
    float s2 = d * d;
    for (int off = 32; off >= 1; off >>= 1) s2 += __shfl_xor(s2, off, 64);
    float var = s2 * (1.0f / 64.0f);
    float h = d / sqrtf(var + 1e-5f) * A[A_GAMMA + j] + A[A_BETA + j];
    hrow[j] = h;
    __syncthreads();

    if (j < 32) {
        float sv = A[A_BS + j];
        for (int k = 0; k < 64; ++k)
            sv = fmaf(hrow[k], A[A_WSM + k * 32 + j], sv);
        float n2 = sv * sv;
        for (int off = 16; off >= 1; off >>= 1) n2 += __shfl_xor(n2, off, 64);
        float nrm = fmaxf(sqrtf(n2), 1e-12f);
        tbl[v * 32 + j] = sv;
        tbl[2048 + v * 32 + j] = sv / nrm;
    } else {
        int jj = j - 32;
        float ev = A[A_BE + jj];
        for (int k = 0; k < 64; ++k)
            ev = fmaf(hrow[k], A[A_WEM + k * 32 + jj], ev);
        float n2 = ev * ev;
        for (int off = 16; off >= 1; off >>= 1) n2 += __shfl_xor(n2, off, 64);
        float nrm = fmaxf(sqrtf(n2), 1e-12f);
        tbl[4096 + v * 32 + jj] = ev;
        tbl[6144 + v * 32 + jj] = ev / nrm;
    }
}

// ---------------- Kernel 2: P-only chunk scan, half-row per lane ----------
// grid = NB*32 = 4096 blocks, 256 threads = 4 waves; wave = one (chunk, mat):
// mat = w&1, c = cpair*2 + (w>>1). lane = hf*32 + r owns P[r][hf*16..+15].
#define DOT4(a, b) fmaf((a).x, (b).x, fmaf((a).y, (b).y, fmaf((a).z, (b).z, (a).w * (b).w)))
#define UPD4(p, k) { (p).x = fmaf(cp, (k).x, (p).x); (p).y = fmaf(cp, (k).y, (p).y); \
                     (p).z = fmaf(cp, (k).z, (p).z); (p).w = fmaf(cp, (k).w, (p).w); }

__global__ __launch_bounds__(256, 4) void chunk_scan_p(
    const int* __restrict__ seq, const float* __restrict__ tbl,
    float* __restrict__ Pbuf)
{
    __shared__ float kl[4096];      // [mat][v][j] normalized k tables (16 KB)
    __shared__ int tk[2][CLEN];     // tokens for the block's 2 chunks

    int tid = threadIdx.x;
    int b = blockIdx.x >> 5;        // 32 cpairs per batch
    int cpair = blockIdx.x & 31;
    int c0 = cpair * 2;

    for (int i = tid; i < 2048; i += 256) {
        kl[i] = tbl[2048 + i];          // ks
        kl[2048 + i] = tbl[6144 + i];   // ke
    }
    for (int s = 0; s < 2; ++s) {
        int t0s = (c0 + s) * CLEN;
        for (int i = tid; i < CLEN; i += 256) {
            int t = t0s + i;
            tk[s][i] = (t < NSTEPS) ? seq[b * NL + t] : 0;
        }
    }
    __syncthreads();

    int w = tid >> 6;
    int lane = tid & 63;
    int mat = w & 1;
    int c = c0 + (w >> 1);
    int hf = lane >> 5;             // column half
    int r = lane & 31;              // row

    const float* kt = kl + mat * 2048 + hf * 16;   // this lane's k half base
    const int* tks = tk[w >> 1];

    int t0 = c * CLEN;
    int clen = NSTEPS - t0;
    if (clen > CLEN) clen = CLEN;

    int cbase = hf * 16;            // first owned column
    float4 p0 = make_float4(r == cbase + 0, r == cbase + 1, r == cbase + 2, r == cbase + 3);
    float4 p1 = make_float4(r == cbase + 4, r == cbase + 5, r == cbase + 6, r == cbase + 7);
    float4 p2 = make_float4(r == cbase + 8, r == cbase + 9, r == cbase + 10, r == cbase + 11);
    float4 p3 = make_float4(r == cbase + 12, r == cbase + 13, r == cbase + 14, r == cbase + 15);

    const float bstep = BETA * (1.0f / 4096.0f);
    float bmul = mat ? bstep : 0.0f;
    float badd = mat ? 0.0f : BETA;

    for (int it = 0; it < CLEN; ++it) {
        int v = tks[it];                              // wave-uniform LDS b32
        const float4* kp = (const float4*)(kt + v * 32);
        float4 k0 = kp[0], k1 = kp[1], k2 = kp[2], k3 = kp[3];
        float bsc = fmaf(bmul, (float)(t0 + it + 1), badd);
        if (it >= clen) bsc = 0.0f;                   // mask pad step

        // partial dot over the 16 owned columns, combine across halves
        float part = (DOT4(p0, k0) + DOT4(p1, k1)) + (DOT4(p2, k2) + DOT4(p3, k3));
        float dp = part + __shfl_xor(part, 32, 64);   // (P k)[r]
        float cp = -bsc * dp;
        UPD4(p0, k0) UPD4(p1, k1) UPD4(p2, k2) UPD4(p3, k3)
    }

    float4* pd = (float4*)(Pbuf + (((size_t)b * 2 + mat) * CCH + c) * 1024
                           + r * 32 + hf * 16);
    pd[0] = p0; pd[1] = p1; pd[2] = p2; pd[3] = p3;
}

// ---------------- Kernel 3: fold z backward across chunks -----------------
// grid = NB*2 blocks (1 per (b,mat)), 64 threads. z starts at q; for
// c = CCH-1..0: store zin[c] = z; z = P_c z. Next chunk's P row prefetched.
__global__ __launch_bounds__(64, 1) void fold_z(
    const int* __restrict__ seq, const float* __restrict__ tbl,
    const float* __restrict__ Pbuf, float* __restrict__ zin)
{
    __shared__ float zl[32];
    int bm = blockIdx.x;
    int b = bm >> 1, mat = bm & 1;
    int lane = threadIdx.x;
    int r = lane & 31;
    int act = (lane < 32);

    int vlast = seq[b * NL + NL - 1];
    if (act) zl[lane] = tbl[2048 + mat * 4096 + vlast * 32 + lane];
    __syncthreads();

    const float* Pb = Pbuf + (size_t)bm * CCH * 1024;
    float4 cur[8];
    if (act) {
        const float4* src = (const float4*)(Pb + (size_t)(CCH - 1) * 1024 + r * 32);
#pragma unroll
        for (int i = 0; i < 8; ++i) cur[i] = src[i];
    }

    for (int c = CCH - 1; c >= 0; --c) {
        if (act) zin[((size_t)bm * CCH + c) * 32 + r] = zl[r];
        float4 nxt[8];
        if (act && c > 0) {
            const float4* src = (const float4*)(Pb + (size_t)(c - 1) * 1024 + r * 32);
#pragma unroll
            for (int i = 0; i < 8; ++i) nxt[i] = src[i];    // indep of zl
        }
        float y = 0.0f;
        if (act) {
            float a0 = 0.f, a1 = 0.f, a2 = 0.f, a3 = 0.f;
#pragma unroll
            for (int i = 0; i < 8; ++i) {
                const float* zp = zl + 4 * i;
                a0 = fmaf(cur[i].x, zp[0], a0);
                a1 = fmaf(cur[i].y, zp[1], a1);
                a2 = fmaf(cur[i].z, zp[2], a2);
                a3 = fmaf(cur[i].w, zp[3], a3);
            }
            y = (a0 + a1) + (a2 + a3);
        }
        __syncthreads();
        if (act) zl[r] = y;
        __syncthreads();
        if (act && c > 0) {
#pragma unroll
            for (int i = 0; i < 8; ++i) cur[i] = nxt[i];
        }
    }
}

// ---------------- Kernel 4: per-chunk backward vector scans + reduce ------
// grid = NB*2 blocks (b,mat), 64 threads; lane = chunk. 64-step backward
// scan per lane: d = b*(k.z); racc += d*h; z -= d*k. k/h in 33-padded LDS;
// tokens staged transposed (bank-safe). In-block reduction -> rvbuf[bm*32+j].
__global__ __launch_bounds__(64, 1) void suffix_scan(
    const int* __restrict__ seq, const float* __restrict__ tbl,
    const float* __restrict__ zin, float* __restrict__ rvbuf)
{
    __shared__ float klp[64 * 33];
    __shared__ float hlp[64 * 33];
    __shared__ int tkT[64 * 64];    // [it][c]
    __shared__ float red[64 * 33];

    int bm = blockIdx.x;
    int b = bm >> 1, mat = bm & 1;
    int lane = threadIdx.x;

    for (int i = lane; i < 2048; i += 64) {
        int v = i >> 5, j = i & 31;
        klp[v * 33 + j] = tbl[2048 + mat * 4096 + i];
        hlp[v * 33 + j] = tbl[mat * 4096 + i];
    }
    for (int i = lane; i < 4096; i += 64) {
        int c = i >> 6, it = i & 63;
        tkT[it * 64 + c] = seq[b * NL + i];     // coalesced read, scatter store
    }
    __syncthreads();

    int c = lane;
    int t0 = c * CLEN;
    float z[32], racc[32];
    const float* zsrc = zin + ((size_t)bm * CCH + c) * 32;
#pragma unroll
    for (int j = 0; j < 32; ++j) { z[j] = zsrc[j]; racc[j] = 0.0f; }

    const float bstep = BETA * (1.0f / 4096.0f);
    float bmul = mat ? bstep : 0.0f;
    float badd = mat ? 0.0f : BETA;

    for (int it = CLEN - 1; it >= 0; --it) {
        int t = t0 + it;
        int v = tkT[it * 64 + c];
        const float* kp = klp + v * 33;
        const float* hp = hlp + v * 33;
        float bsc = fmaf(bmul, (float)(t + 1), badd);
        if (t >= NSTEPS) bsc = 0.0f;

        float d0 = 0.f, d1 = 0.f, d2 = 0.f, d3 = 0.f;
#pragma unroll
        for (int j = 0; j < 32; j += 4) {
            d0 = fmaf(z[j + 0], kp[j + 0], d0);
            d1 = fmaf(z[j + 1], kp[j + 1], d1);
            d2 = fmaf(z[j + 2], kp[j + 2], d2);
            d3 = fmaf(z[j + 3], kp[j + 3], d3);
        }
        float d = ((d0 + d1) + (d2 + d3)) * bsc;
#pragma unroll
        for (int j = 0; j < 32; ++j) {
            racc[j] = fmaf(d, hp[j], racc[j]);
            z[j] = fmaf(-d, kp[j], z[j]);
        }
    }

#pragma unroll
    for (int j = 0; j < 32; ++j) red[lane * 33 + j] = racc[j];
    __syncthreads();
    if (lane < 32) {
        float s = 0.0f;
        for (int l = 0; l < 64; ++l) s += red[l * 33 + lane];
        rvbuf[(size_t)bm * 32 + lane] = s;
    }
}

// ---------------- Kernel 5: readout projections ---------------------------
__global__ __launch_bounds__(64, 2) void reduce_readout(
    const float* __restrict__ rvbuf, const float* __restrict__ A,
    const void* ln_g, void* __restrict__ outv)
{
    __shared__ float rv[64];
    __shared__ float o1s[64];
    int b = blockIdx.x;
    int tid = threadIdx.x;

    rv[tid] = rvbuf[b * 64 + tid];   // [rs | re]
    __syncthreads();
    float o = A[A_BRP + tid];
    for (int i = 0; i < 64; ++i)
        o = fmaf(rv[i], A[A_WRP + i * 64 + tid], o);
    o1s[tid] = o;
    __syncthreads();
    float o2 = A[A_BOUT + tid];
    for (int i = 0; i < 64; ++i)
        o2 = fmaf(o1s[i], A[A_WOUT + i * 64 + tid], o2);
    int isbf = (*(const uint32_t*)ln_g == 0x3F803F80u) ? 1 : 0;
    if (isbf)
        ((__hip_bfloat16*)outv)[b * 64 + tid] = __float2bfloat16(o2);
    else
        ((float*)outv)[b * 64 + tid] = o2;
}

extern "C" void kernel_launch(void* const* d_in, const int* in_sizes, int n_in,
                              void* d_out, int out_size, void* d_ws, size_t ws_size,
                              hipStream_t stream) {
    const int* seq = (const int*)d_in[0];
    Ptrs ps;
    for (int i = 0; i < 15; ++i) ps.p[i] = d_in[i + 1];
    const void* ln_g = d_in[6];

    // ws (floats): arena[33280] | tbl[8192] | Pbuf[256*64*1024] | zin | rvbuf
    float* arena = (float*)d_ws;
    float* tbl = arena + A_TOTAL;
    float* Pbuf = tbl + 8192;
    size_t PN = (size_t)NB * 2 * CCH * 1024;   // 16.8M floats
    float* zinb = Pbuf + PN;
    size_t ZN = (size_t)NB * 2 * CCH * 32;     // 524k floats
    float* rvbuf = zinb + ZN;

    convert_inputs<<<15, 256, 0, stream>>>(ps, arena);
    build_tables<<<64, 64, 0, stream>>>(arena, tbl);
    chunk_scan_p<<<NB * 32, 256, 0, stream>>>(seq, tbl, Pbuf);
    fold_z<<<NB * 2, 64, 0, stream>>>(seq, tbl, Pbuf, zinb);
    suffix_scan<<<NB * 2, 64, 0, stream>>>(seq, tbl, zinb, rvbuf);
    reduce_readout<<<NB, 64, 0, stream>>>(rvbuf, arena, ln_g, d_out);
}